// Round 25
// baseline (1011.487 us; speedup 1.0000x reference)
//
#include <hip/hip_runtime.h>
#include <hip/hip_bf16.h>
#include <math.h>

typedef short bf16x8 __attribute__((ext_vector_type(8)));
typedef float f32x4 __attribute__((ext_vector_type(4)));
using bf16_t = __hip_bfloat16;

#define DEV static __device__ __forceinline__

DEV unsigned short f2bu(float x) {
  bf16_t h = __float2bfloat16(x);
  unsigned short u;
  __builtin_memcpy(&u, &h, 2);
  return u;
}
DEV void st4(bf16_t* p, float a, float b, float c, float d) {
  ushort4 u;
  u.x = f2bu(a); u.y = f2bu(b); u.z = f2bu(c); u.w = f2bu(d);
  *reinterpret_cast<ushort4*>(p) = u;
}

// bijective XCD swizzle (m204)
DEV int xcd_swz(int orig, int tot) {
  int q = tot >> 3, r = tot & 7;
  int xcd = orig & 7, pos = orig >> 3;
  int base = xcd < r ? xcd * (q + 1) : r * (q + 1) + (xcd - r) * q;
  return base + pos;
}

// async 16B/lane global -> LDS (wave-uniform LDS base + lane*16)
DEV void async_copy16(const bf16_t* g, bf16_t* lds) {
  __builtin_amdgcn_global_load_lds(
      (const __attribute__((address_space(1))) unsigned int*)g,
      (__attribute__((address_space(3))) unsigned int*)lds, 16, 0, 0);
}

// ---------------- batched weight transpose (13 square 768x768 weights, per-entry scale) --------
struct WPack {
  const float* s[13];
  bf16_t* d[13];
  float scale[13];
};

__global__ __launch_bounds__(256) void k_wt13(WPack pk) {
  __shared__ float tile[32][33];
  int z = blockIdx.z;
  const float* W = pk.s[z];
  bf16_t* WT = pk.d[z];
  float scale = pk.scale[z];
  int i0 = blockIdx.x * 32;
  int o0 = blockIdx.y * 32;
  int tx = threadIdx.x & 31, ty = threadIdx.x >> 5;
  for (int r = ty; r < 32; r += 8)
    tile[r][tx] = W[(size_t)(i0 + r) * 768 + (o0 + tx)];
  __syncthreads();
  for (int r = ty; r < 32; r += 8)
    WT[(size_t)(o0 + r) * 768 + (i0 + tx)] = __float2bfloat16(tile[tx][r] * scale);
}

// ---------------- single weight transpose + bf16 convert: W[in][out] -> WT[out][in] ----------------
__global__ __launch_bounds__(256) void k_wt(const float* __restrict__ W, bf16_t* __restrict__ WT,
                                            int in_dim, int out_dim) {
  __shared__ float tile[32][33];
  int i0 = blockIdx.x * 32;
  int o0 = blockIdx.y * 32;
  int tx = threadIdx.x & 31, ty = threadIdx.x >> 5;
  for (int r = ty; r < 32; r += 8)
    tile[r][tx] = W[(size_t)(i0 + r) * out_dim + (o0 + tx)];
  __syncthreads();
  for (int r = ty; r < 32; r += 8)
    WT[(size_t)(o0 + r) * in_dim + (i0 + tx)] = __float2bfloat16(tile[tx][r]);
}

// ---------------- bias concat: out = [s0*a0 ; s1 ; s2] (segments of 768) ----------------
__global__ __launch_bounds__(256) void k_bcat(const float* __restrict__ s0, const float* __restrict__ s1,
                                              const float* __restrict__ s2, float a0,
                                              float* __restrict__ out, int nseg) {
  int i = blockIdx.x * 256 + threadIdx.x;
  if (i >= nseg * 768) return;
  int seg = i / 768, c = i - seg * 768;
  const float* s = seg == 0 ? s0 : (seg == 1 ? s1 : s2);
  out[i] = s[c] * (seg == 0 ? a0 : 1.0f);
}

// ---------------- stage-1 elementwise prep ----------------
__global__ __launch_bounds__(256) void k_prep1(const float4* __restrict__ q, const float4* __restrict__ ce,
                                               const float4* __restrict__ pe,
                                               bf16_t* __restrict__ qpe_b, bf16_t* __restrict__ q0_b, int n4) {
  int i = blockIdx.x * 256 + threadIdx.x;
  if (i >= n4) return;
  float4 a = q[i], b = ce[i], p = pe[i];
  float sx = a.x + b.x, sy = a.y + b.y, sz = a.z + b.z, sw = a.w + b.w;
  st4(q0_b + 4 * (size_t)i, sx, sy, sz, sw);
  st4(qpe_b + 4 * (size_t)i, sx + p.x, sy + p.y, sz + p.z, sw + p.w);
}

// ---------------- build qq (=img+pe+flag) and imAB (=raw img) for rows = 2B*N ----------------
__global__ __launch_bounds__(256) void k_buildqq(const float* __restrict__ imA, const float* __restrict__ imB,
                                                 const float* __restrict__ pe, const float* __restrict__ fa,
                                                 const float* __restrict__ fb, bf16_t* __restrict__ qq,
                                                 bf16_t* __restrict__ imAB) {
  int idx = blockIdx.x * 256 + threadIdx.x;
  int c4 = idx % 192; int rem = idx / 192;
  int n = rem & 1023; int bb = rem >> 10;
  int b = bb & 3, isB = bb >> 2;
  int c = c4 * 4;
  size_t tok = (size_t)(b * 1024 + n) * 768 + c;
  float4 s = *(const float4*)((isB ? imB : imA) + tok);
  float4 p = *(const float4*)(pe + tok);
  float4 f = *(const float4*)((isB ? fb : fa) + c);
  size_t o = (size_t)rem * 768 + c;
  st4(imAB + o, s.x, s.y, s.z, s.w);
  st4(qq + o, s.x + p.x + f.x, s.y + p.y + f.y, s.z + p.z + f.z, s.w + p.w + f.w);
}

// ---------------- flash attention with segmented K/V; T14 async-STAGE split --------------
// Tile t+1's K/V loads are issued right after the opening barrier and fly under tile t's
// compute in registers; they commit to LDS at the top of the next iteration (after the
// closing barrier guarantees all waves finished reading tile t). Same arithmetic as r23.
struct FArgs {
  const bf16_t* Q; bf16_t* O;
  const bf16_t* Kp[3]; const bf16_t* Vp[3];
  int badd[3], bmask[3];
  int ldq, ldk;
  long qStrideB, oStrideB;
};

template<int NSEG>
__global__ __launch_bounds__(256, 3) void k_flash(FArgs fa) {
  const int z = blockIdx.y; const int b = z / 6, h = z % 6;
  const bf16_t* Qb = fa.Q + (size_t)b * fa.qStrideB + h * 128;
  bf16_t* Ob = fa.O + (size_t)b * fa.oStrideB + h * 128;
  const int q0 = blockIdx.x * 64;
  const int tid = threadIdx.x, lane = tid & 63, w = tid >> 6;
  const int g = lane >> 4, c = lane & 15;

  __shared__ bf16_t Ks[64][136];
  __shared__ bf16_t Vs[128][72];
  __shared__ bf16_t Ps[64][72];

  bf16x8 qf[4];
#pragma unroll
  for (int kk = 0; kk < 4; kk++)
    qf[kk] = *reinterpret_cast<const bf16x8*>(
        &Qb[(size_t)(q0 + w * 16 + c) * fa.ldq + kk * 32 + g * 8]);

  f32x4 oa[8];
  float m[4], l[4];
#pragma unroll
  for (int d = 0; d < 8; d++) { f32x4 zz = {0.f, 0.f, 0.f, 0.f}; oa[d] = zz; }
#pragma unroll
  for (int r = 0; r < 4; r++) { m[r] = -1.0e30f; l[r] = 0.f; }

  const int kr_ = tid >> 4, kc_ = (tid & 15) * 8;   // K: 16 rows/pass
  const int vr_ = tid >> 3, vc_ = (tid & 7) * 8;    // V: 32 rows/pass
  const int ldk = fa.ldk;
  const int NT = NSEG * 16;

  uint4 kg[4], vg[4];
  auto issue = [&](int t) {
    const int s = t >> 4;
    const int bi = fa.badd[s] + (b & fa.bmask[s]);
    const bf16_t* Kb = fa.Kp[s] + (size_t)bi * 1024 * ldk + h * 128;
    const bf16_t* Vb = fa.Vp[s] + (size_t)(bi * 6 + h) * 128 * 1024;
    const int k0 = (t & 15) << 6;
#pragma unroll
    for (int p = 0; p < 4; p++)
      kg[p] = *reinterpret_cast<const uint4*>(&Kb[(size_t)(k0 + p * 16 + kr_) * ldk + kc_]);
#pragma unroll
    for (int p = 0; p < 4; p++)
      vg[p] = *reinterpret_cast<const uint4*>(&Vb[(size_t)(p * 32 + vr_) * 1024 + k0 + vc_]);
  };

  issue(0);
  for (int t = 0; t < NT; ++t) {
    // commit tile t (safe: closing barrier of t-1 drained all reads of the old tile)
#pragma unroll
    for (int p = 0; p < 4; p++)
      *reinterpret_cast<uint4*>(&Ks[p * 16 + kr_][kc_]) = kg[p];
#pragma unroll
    for (int p = 0; p < 4; p++)
      *reinterpret_cast<uint4*>(&Vs[p * 32 + vr_][vc_]) = vg[p];
    __syncthreads();

    if (t + 1 < NT) issue(t + 1);   // fly under compute

    f32x4 sx[4];
#pragma unroll
    for (int j = 0; j < 4; j++) { f32x4 zz = {0.f, 0.f, 0.f, 0.f}; sx[j] = zz; }
    __builtin_amdgcn_s_setprio(1);
#pragma unroll
    for (int kk = 0; kk < 4; kk++)
#pragma unroll
      for (int j = 0; j < 4; j++) {
        bf16x8 kf = *reinterpret_cast<const bf16x8*>(&Ks[j * 16 + c][kk * 32 + g * 8]);
        sx[j] = __builtin_amdgcn_mfma_f32_16x16x32_bf16(qf[kk], kf, sx[j], 0, 0, 0);
      }
    __builtin_amdgcn_s_setprio(0);

    float tl[4];
#pragma unroll
    for (int r = 0; r < 4; r++)
      tl[r] = fmaxf(fmaxf(sx[0][r], sx[1][r]), fmaxf(sx[2][r], sx[3][r]));
    float ex = fmaxf(fmaxf(tl[0] - m[0], tl[1] - m[1]), fmaxf(tl[2] - m[2], tl[3] - m[3]));
    if (__any(ex > 8.0f)) {
#pragma unroll
      for (int r = 0; r < 4; r++) {
        float tv = tl[r];
        tv = fmaxf(tv, __shfl_xor(tv, 1));
        tv = fmaxf(tv, __shfl_xor(tv, 2));
        tv = fmaxf(tv, __shfl_xor(tv, 4));
        tv = fmaxf(tv, __shfl_xor(tv, 8));
        float mn = fmaxf(m[r], tv);
        float f = exp2f(m[r] - mn);
        m[r] = mn;
        l[r] *= f;
#pragma unroll
        for (int d = 0; d < 8; d++) oa[d][r] *= f;
      }
    }
#pragma unroll
    for (int j = 0; j < 4; j++)
#pragma unroll
      for (int r = 0; r < 4; r++) {
        float p = exp2f(sx[j][r] - m[r]);
        l[r] += p;
        Ps[w * 16 + g * 4 + r][j * 16 + c] = __float2bfloat16(p);
      }

    __builtin_amdgcn_s_setprio(1);
#pragma unroll
    for (int kk = 0; kk < 2; kk++) {
      bf16x8 pf = *reinterpret_cast<const bf16x8*>(&Ps[w * 16 + c][kk * 32 + g * 8]);
#pragma unroll
      for (int d = 0; d < 8; d++) {
        bf16x8 vf = *reinterpret_cast<const bf16x8*>(&Vs[d * 16 + c][kk * 32 + g * 8]);
        oa[d] = __builtin_amdgcn_mfma_f32_16x16x32_bf16(pf, vf, oa[d], 0, 0, 0);
      }
    }
    __builtin_amdgcn_s_setprio(0);
    __syncthreads();
  }

  float inv[4];
#pragma unroll
  for (int r = 0; r < 4; r++) {
    float t2 = l[r];
    t2 += __shfl_xor(t2, 1);
    t2 += __shfl_xor(t2, 2);
    t2 += __shfl_xor(t2, 4);
    t2 += __shfl_xor(t2, 8);
    inv[r] = 1.0f / t2;
  }
#pragma unroll
  for (int d = 0; d < 8; d++) {
    int col = d * 16 + c;
#pragma unroll
    for (int r = 0; r < 4; r++) {
      int row = q0 + w * 16 + g * 4 + r;
      Ob[(size_t)row * 768 + col] = __float2bfloat16(oa[d][r] * inv[r]);
    }
  }
}

// ---------------- fused residual + LayerNorm (+ optional pe/flag bf16 output) ----------------
__global__ __launch_bounds__(256) void k_ln(const float* __restrict__ X1, const float* __restrict__ X2,
                                            const float* __restrict__ A,
                                            const float* __restrict__ w, const float* __restrict__ bvec,
                                            float* __restrict__ outf, bf16_t* __restrict__ outb,
                                            const float* __restrict__ pe, const float* __restrict__ flag,
                                            bf16_t* __restrict__ outpf) {
  int row = blockIdx.x, tid = threadIdx.x;
  size_t base = (size_t)row * 768;
  float v0 = X1[base + tid] + A[base + tid];
  float v1 = X1[base + tid + 256] + A[base + tid + 256];
  float v2 = X1[base + tid + 512] + A[base + tid + 512];
  if (X2) {
    v0 += X2[base + tid]; v1 += X2[base + tid + 256]; v2 += X2[base + tid + 512];
  }
  float s = v0 + v1 + v2;
  for (int o = 32; o; o >>= 1) s += __shfl_xor(s, o);
  __shared__ float sm[8];
  int wv = tid >> 6, ln = tid & 63;
  if (ln == 0) sm[wv] = s;
  __syncthreads();
  s = sm[0] + sm[1] + sm[2] + sm[3];
  float mean = s * (1.0f / 768.0f);
  float d0 = v0 - mean, d1 = v1 - mean, d2 = v2 - mean;
  float ss = d0 * d0 + d1 * d1 + d2 * d2;
  for (int o = 32; o; o >>= 1) ss += __shfl_xor(ss, o);
  if (ln == 0) sm[4 + wv] = ss;
  __syncthreads();
  ss = sm[4] + sm[5] + sm[6] + sm[7];
  float rstd = rsqrtf(ss * (1.0f / 768.0f) + 1e-5f);
  float o0 = d0 * rstd * w[tid] + bvec[tid];
  float o1 = d1 * rstd * w[tid + 256] + bvec[tid + 256];
  float o2 = d2 * rstd * w[tid + 512] + bvec[tid + 512];
  outf[base + tid] = o0; outf[base + tid + 256] = o1; outf[base + tid + 512] = o2;
  if (outb) {
    outb[base + tid] = __float2bfloat16(o0);
    outb[base + tid + 256] = __float2bfloat16(o1);
    outb[base + tid + 512] = __float2bfloat16(o2);
  }
  if (outpf) {
    outpf[base + tid] = __float2bfloat16(o0 + pe[base + tid] + flag[tid]);
    outpf[base + tid + 256] = __float2bfloat16(o1 + pe[base + tid + 256] + flag[tid + 256]);
    outpf[base + tid + 512] = __float2bfloat16(o2 + pe[base + tid + 512] + flag[tid + 512]);
  }
}

// ---------------- packed multi-GEMM (up to 7), with per-768-col output split ----------------
struct GArgs {
  const bf16_t* X; const bf16_t* Wt; const float* bias;
  void* O0; void* O1; void* O2;
  const bf16_t* resid;
  int K, ldx, ldw, ldo, vNk, mode;
};
struct GPack {
  GArgs a[7];
  int cum[7];
  int nx[7];
  int tot;
};

__global__ __launch_bounds__(256, 2) void k_gemmN(GPack pk) {
  GArgs a; int gbase, nx;
  int sidx = xcd_swz(blockIdx.x, pk.tot);
  {
    int idx = sidx;
    if (idx < pk.cum[0])      { a = pk.a[0]; gbase = 0;          nx = pk.nx[0]; }
    else if (idx < pk.cum[1]) { a = pk.a[1]; gbase = pk.cum[0];  nx = pk.nx[1]; }
    else if (idx < pk.cum[2]) { a = pk.a[2]; gbase = pk.cum[1];  nx = pk.nx[2]; }
    else if (idx < pk.cum[3]) { a = pk.a[3]; gbase = pk.cum[2];  nx = pk.nx[3]; }
    else if (idx < pk.cum[4]) { a = pk.a[4]; gbase = pk.cum[3];  nx = pk.nx[4]; }
    else if (idx < pk.cum[5]) { a = pk.a[5]; gbase = pk.cum[4];  nx = pk.nx[5]; }
    else                      { a = pk.a[6]; gbase = pk.cum[5];  nx = pk.nx[6]; }
  }
  int idx = sidx - gbase;
  const int brow = (idx / nx) * 128;
  const int bcol = (idx % nx) * 128;

  __shared__ bf16_t As[128 * 32];
  __shared__ bf16_t Bs[128 * 32];

  const int tid = threadIdx.x;
  const int lane = tid & 63;
  const int wave = tid >> 6;
  const int wr = wave >> 1;
  const int wc = wave & 1;

  f32x4 acc[4][4];
#pragma unroll
  for (int i = 0; i < 4; i++)
#pragma unroll
    for (int j = 0; j < 4; j++) {
      f32x4 zz = {0.f, 0.f, 0.f, 0.f};
      acc[i][j] = zz;
    }

  const int sr = lane >> 2;
  const int sc = (lane & 3) * 8;
  const int lrow = lane & 15;
  const int kch = (lane >> 4) * 8;

  const int nK = a.K >> 5;
  for (int kk = 0; kk < nK; ++kk) {
    const int k0 = kk << 5;
#pragma unroll
    for (int q = 0; q < 2; q++) {
      const int rows = wave * 32 + q * 16;
      async_copy16(a.X + (size_t)(brow + rows + sr) * a.ldx + k0 + sc, As + rows * 32);
      async_copy16(a.Wt + (size_t)(bcol + rows + sr) * a.ldw + k0 + sc, Bs + rows * 32);
    }
    __syncthreads();

    bf16x8 afr[4], bfr[4];
#pragma unroll
    for (int i = 0; i < 4; i++)
      afr[i] = *reinterpret_cast<const bf16x8*>(&As[(wr * 64 + i * 16 + lrow) * 32 + kch]);
#pragma unroll
    for (int j = 0; j < 4; j++)
      bfr[j] = *reinterpret_cast<const bf16x8*>(&Bs[(wc * 64 + j * 16 + lrow) * 32 + kch]);
#pragma unroll
    for (int i = 0; i < 4; i++)
#pragma unroll
      for (int j = 0; j < 4; j++)
        acc[i][j] = __builtin_amdgcn_mfma_f32_16x16x32_bf16(afr[i], bfr[j], acc[i][j], 0, 0, 0);
    __syncthreads();
  }

  const int lcol = lane & 15;
  const int lrow4 = (lane >> 4) * 4;

  int seg = 0;
  if (a.O1) seg = bcol / 768;
  void* ob = seg == 0 ? a.O0 : (seg == 1 ? a.O1 : a.O2);
  const int cofs = seg * 768;

  if (a.mode == 2) {
    const int bi = brow / a.vNk;
    const int n0 = brow - bi * a.vNk;
#pragma unroll
    for (int i = 0; i < 4; i++) {
      int rloc = n0 + wr * 64 + i * 16 + lrow4;
#pragma unroll
      for (int j = 0; j < 4; j++) {
        int colf = bcol + wc * 64 + j * 16 + lcol;
        int col = colf - cofs;
        int hh = col >> 7, dd = col & 127;
        float bv = a.bias[colf];
        ushort4 u;
        u.x = f2bu(acc[i][j][0] + bv);
        u.y = f2bu(acc[i][j][1] + bv);
        u.z = f2bu(acc[i][j][2] + bv);
        u.w = f2bu(acc[i][j][3] + bv);
        bf16_t* dst = reinterpret_cast<bf16_t*>(ob) +
                      ((size_t)(bi * 6 + hh) * 128 + dd) * (size_t)a.vNk + rloc;
        *reinterpret_cast<ushort4*>(dst) = u;
      }
    }
  } else if (a.mode == 3) {
#pragma unroll
    for (int i = 0; i < 4; i++) {
      int row0 = brow + wr * 64 + i * 16 + lrow4;
#pragma unroll
      for (int j = 0; j < 4; j++) {
        int col = bcol + wc * 64 + j * 16 + lcol;
        float bv = a.bias[col];
#pragma unroll
        for (int r = 0; r < 4; r++) {
          size_t idx2 = (size_t)(row0 + r) * a.ldo + col;
          float rv = __bfloat162float(a.resid[(size_t)(row0 + r) * 768 + col]);
          reinterpret_cast<float*>(a.O0)[idx2] = acc[i][j][r] + bv + rv;
        }
      }
    }
  } else {
#pragma unroll
    for (int i = 0; i < 4; i++) {
      int row0 = brow + wr * 64 + i * 16 + lrow4;
#pragma unroll
      for (int j = 0; j < 4; j++) {
        int colf = bcol + wc * 64 + j * 16 + lcol;
        int col = colf - cofs;
        float bv = a.bias[colf];
#pragma unroll
        for (int r = 0; r < 4; r++)
          reinterpret_cast<bf16_t*>(ob)[(size_t)(row0 + r) * a.ldo + col] =
              __float2bfloat16(acc[i][j][r] + bv);
      }
    }
  }
}

static inline void packN(hipStream_t st, const GArgs* as, const int* Ms, const int* Ns, int n) {
  GPack pk;
  int tot = 0;
  for (int i = 0; i < 7; ++i) {
    int j = i < n ? i : n - 1;
    pk.a[i] = as[j];
    pk.nx[i] = Ns[j] / 128;
    if (i < n) tot += (Ns[j] / 128) * (Ms[j] / 128);
    pk.cum[i] = tot;
  }
  pk.tot = tot;
  k_gemmN<<<dim3(tot), 256, 0, st>>>(pk);
}

// ---------------- single bf16 MFMA GEMM (f32/bf16 out, optional GELU), T1-swizzled ----------------
template<int OUTBF, int GELU>
__global__ __launch_bounds__(256, 2) void k_gemm(
    const bf16_t* __restrict__ X, const bf16_t* __restrict__ Wt,
    const float* __restrict__ bias, void* __restrict__ Out,
    int M, int Nout, int K, int ldx, int ldw, int ldo, float alpha) {
  int tot = gridDim.x * gridDim.y;
  int lin = blockIdx.y * gridDim.x + blockIdx.x;
  int sidx = xcd_swz(lin, tot);
  const int brow = (sidx / gridDim.x) * 128;
  const int bcol = (sidx % gridDim.x) * 128;

  __shared__ bf16_t As[128 * 32];
  __shared__ bf16_t Bs[128 * 32];

  const int tid = threadIdx.x;
  const int lane = tid & 63;
  const int wave = tid >> 6;
  const int wr = wave >> 1;
  const int wc = wave & 1;

  f32x4 acc[4][4];
#pragma unroll
  for (int i = 0; i < 4; i++)
#pragma unroll
    for (int j = 0; j < 4; j++) {
      f32x4 zz = {0.f, 0.f, 0.f, 0.f};
      acc[i][j] = zz;
    }

  const int sr = lane >> 2;
  const int sc = (lane & 3) * 8;
  const int lrow = lane & 15;
  const int kch = (lane >> 4) * 8;

  const int nK = K >> 5;
  for (int kk = 0; kk < nK; ++kk) {
    const int k0 = kk << 5;
#pragma unroll
    for (int q = 0; q < 2; q++) {
      const int rows = wave * 32 + q * 16;
      async_copy16(X + (size_t)(brow + rows + sr) * ldx + k0 + sc, As + rows * 32);
      async_copy16(Wt + (size_t)(bcol + rows + sr) * ldw + k0 + sc, Bs + rows * 32);
    }
    __syncthreads();

    bf16x8 afr[4], bfr[4];
#pragma unroll
    for (int i = 0; i < 4; i++)
      afr[i] = *reinterpret_cast<const bf16x8*>(&As[(wr * 64 + i * 16 + lrow) * 32 + kch]);
#pragma unroll
    for (int j = 0; j < 4; j++)
      bfr[j] = *reinterpret_cast<const bf16x8*>(&Bs[(wc * 64 + j * 16 + lrow) * 32 + kch]);
#pragma unroll
    for (int i = 0; i < 4; i++)
#pragma unroll
      for (int j = 0; j < 4; j++)
        acc[i][j] = __builtin_amdgcn_mfma_f32_16x16x32_bf16(afr[i], bfr[j], acc[i][j], 0, 0, 0);
    __syncthreads();
  }

  const int lcol = lane & 15;
  const int lrow4 = (lane >> 4) * 4;

#pragma unroll
  for (int i = 0; i < 4; i++) {
    int row0 = brow + wr * 64 + i * 16 + lrow4;
#pragma unroll
    for (int j = 0; j < 4; j++) {
      int col = bcol + wc * 64 + j * 16 + lcol;
      float bv = bias ? bias[col] : 0.0f;
#pragma unroll
      for (int r = 0; r < 4; r++) {
        float v = (acc[i][j][r] + bv) * alpha;
        if (GELU) v = 0.5f * v * (1.0f + erff(v * 0.70710678118f));
        size_t idx = (size_t)(row0 + r) * ldo + col;
        if (OUTBF) reinterpret_cast<bf16_t*>(Out)[idx] = __float2bfloat16(v);
        else reinterpret_cast<float*>(Out)[idx] = v;
      }
    }
  }
}

static inline void gemm(hipStream_t st, const bf16_t* X, const bf16_t* Wt, const float* bias,
                        void* out, int outBf, int gelu, int M, int N, int K,
                        int ldx, int ldw, int ldo, float alpha = 1.0f) {
  dim3 g(N / 128, M / 128), blk(256);
  if (outBf) {
    if (gelu) k_gemm<1, 1><<<g, blk, 0, st>>>(X, Wt, bias, out, M, N, K, ldx, ldw, ldo, alpha);
    else      k_gemm<1, 0><<<g, blk, 0, st>>>(X, Wt, bias, out, M, N, K, ldx, ldw, ldo, alpha);
  } else      k_gemm<0, 0><<<g, blk, 0, st>>>(X, Wt, bias, out, M, N, K, ldx, ldw, ldo, alpha);
}

extern "C" void kernel_launch(void* const* d_in, const int* in_sizes, int n_in,
                              void* d_out, int out_size, void* d_ws, size_t ws_size,
                              hipStream_t stream) {
  (void)in_sizes; (void)n_in; (void)out_size; (void)ws_size;
  constexpr int B = 4, N = 1024, C = 768, Hh = 6, MLPD = 2304;
  constexpr size_t BNC = (size_t)B * N * C;
  constexpr size_t NC  = (size_t)N * C;
  const float qalpha = 0.08838834764831845f * 1.4426950408889634f;   // 1/sqrt(128) * log2(e)

  const float* queries = (const float*)d_in[0];
  const float* change  = (const float*)d_in[1];
  const float* imA     = (const float*)d_in[2];
  const float* imB     = (const float*)d_in[3];
  const float* pe      = (const float*)d_in[4];
  const float* bq1 = (const float*)d_in[6];  const float* bk1 = (const float*)d_in[8];
  const float* bv1 = (const float*)d_in[10]; const float* bo1 = (const float*)d_in[12];
  const float* bq2 = (const float*)d_in[14]; const float* bk2 = (const float*)d_in[16];
  const float* bv2 = (const float*)d_in[18]; const float* bo2 = (const float*)d_in[20];
  const float* bq3 = (const float*)d_in[22]; const float* bk3 = (const float*)d_in[24];
  const float* bv3 = (const float*)d_in[26]; const float* bo3 = (const float*)d_in[28];
  const float* ln1w = (const float*)d_in[29]; const float* ln1b = (const float*)d_in[30];
  const float* ln2w = (const float*)d_in[31]; const float* ln2b = (const float*)d_in[32];
  const float* ln3w = (const float*)d_in[33]; const float* ln3b = (const float*)d_in[34];
  const float* mb1 = (const float*)d_in[36]; const float* mb2 = (const float*)d_in[38];
  const float* fa = (const float*)d_in[39];
  const float* fb = (const float*)d_in[40];
  const float* fc = (const float*)d_in[41];

  char* base = (char*)d_ws;
  size_t off = 0;
  auto alloc = [&](size_t bytes) -> void* {
    void* p = base + off;
    off += (bytes + 255) & ~(size_t)255;
    return p;
  };

  // ---- persistent weights; ORDER MATTERS (merged views need adjacency) ----
  bf16_t* WT[12]; bf16_t* WT5b; bf16_t* WTm1; bf16_t* WTm2;
  WT[0] = (bf16_t*)alloc((size_t)768 * 768 * 2);
  WT[1] = (bf16_t*)alloc((size_t)768 * 768 * 2);
  WT[2] = (bf16_t*)alloc((size_t)768 * 768 * 2);
  WT[3] = (bf16_t*)alloc((size_t)768 * 768 * 2);
  WT[8] = (bf16_t*)alloc((size_t)768 * 768 * 2);   // Km view: [Wq3|Wk2|Wk3]
  WT[5] = (bf16_t*)alloc((size_t)768 * 768 * 2);
  WT[9] = (bf16_t*)alloc((size_t)768 * 768 * 2);
  WT[6] = (bf16_t*)alloc((size_t)768 * 768 * 2);   // Vm view: [Wv2|Wv3]
  WT[10] = (bf16_t*)alloc((size_t)768 * 768 * 2);
  WT[4] = (bf16_t*)alloc((size_t)768 * 768 * 2);   // Q2K2 view: [Wq2|Wk2']
  WT5b  = (bf16_t*)alloc((size_t)768 * 768 * 2);
  WT[7] = (bf16_t*)alloc((size_t)768 * 768 * 2);
  WT[11] = (bf16_t*)alloc((size_t)768 * 768 * 2);
  WTm1 = (bf16_t*)alloc((size_t)768 * 2304 * 2);
  WTm2 = (bf16_t*)alloc((size_t)2304 * 768 * 2);
  float* bqk1  = (float*)alloc(1536 * 4);
  float* bKm   = (float*)alloc(2304 * 4);
  float* bVm   = (float*)alloc(1536 * 4);
  float* bQ2K2 = (float*)alloc(1536 * 4);
  float*  q1  = (float*)alloc(BNC * 4);
  float*  q2  = (float*)alloc(BNC * 4);
  bf16_t* q2b = (bf16_t*)alloc(BNC * 2);
  bf16_t* q1b = (bf16_t*)alloc(BNC * 2);
  bf16_t* qf  = (bf16_t*)alloc(BNC * 2);
  bf16_t* qq   = (bf16_t*)alloc(2 * BNC * 2);   // img+pe+flag; lives to O3 residual
  bf16_t* Q3h  = (bf16_t*)alloc(2 * BNC * 2);
  bf16_t* K2i  = (bf16_t*)alloc(2 * BNC * 2);
  bf16_t* vT2i = (bf16_t*)alloc(2 * BNC * 2);
  bf16_t* K3i  = (bf16_t*)alloc(2 * BNC * 2);
  bf16_t* vT3i = (bf16_t*)alloc(2 * BNC * 2);
  const size_t arena = off;

  float* dof = (float*)d_out;                  // [0,2BNC) images, [2BNC,3BNC) change
  float* chg = dof + 2 * BNC;

  // weight transposes + bias concats
  {
    WPack pk;
    const int widx[12] = {5, 7, 9, 11, 13, 15, 17, 19, 21, 23, 25, 27};
    for (int i = 0; i < 12; i++) {
      pk.s[i] = (const float*)d_in[widx[i]];
      pk.d[i] = WT[i];
      pk.scale[i] = (i == 0 || i == 4 || i == 8) ? qalpha : 1.0f;
    }
    pk.s[12] = (const float*)d_in[15]; pk.d[12] = WT5b; pk.scale[12] = 1.0f;
    k_wt13<<<dim3(24, 24, 13), 256, 0, stream>>>(pk);
  }
  k_wt<<<dim3(24, 72), 256, 0, stream>>>((const float*)d_in[35], WTm1, 768, 2304);
  k_wt<<<dim3(72, 24), 256, 0, stream>>>((const float*)d_in[37], WTm2, 2304, 768);
  k_bcat<<<dim3(6), 256, 0, stream>>>(bq1, bk1, nullptr, qalpha, bqk1, 2);
  k_bcat<<<dim3(9), 256, 0, stream>>>(bq3, bk2, bk3, qalpha, bKm, 3);
  k_bcat<<<dim3(6), 256, 0, stream>>>(bv2, bv3, nullptr, 1.0f, bVm, 2);
  k_bcat<<<dim3(6), 256, 0, stream>>>(bq2, bk2, nullptr, qalpha, bQ2K2, 2);

  // ================= stage 1 + all input-only projections =================
  off = arena;
  bf16_t* qpe_b = (bf16_t*)alloc(BNC * 2);
  bf16_t* q0_b  = (bf16_t*)alloc(BNC * 2);
  bf16_t* imAB  = (bf16_t*)alloc(2 * BNC * 2);
  bf16_t* QKh   = (bf16_t*)alloc((size_t)B * N * 1536 * 2);
  bf16_t* vT1   = (bf16_t*)alloc(BNC * 2);
  bf16_t* attC  = (bf16_t*)alloc(BNC * 2);
  float*  a1    = dof;

  k_prep1<<<dim3((int)(BNC / 4 / 256)), 256, 0, stream>>>(
      (const float4*)queries, (const float4*)change, (const float4*)pe, qpe_b, q0_b, (int)(BNC / 4));
  k_buildqq<<<dim3((int)(2 * BNC / 4 / 256)), 256, 0, stream>>>(imA, imB, pe, fa, fb, qq, imAB);
  {
    GArgs as[4] = {
      {qpe_b, WT[0], bqk1, QKh,  nullptr, nullptr, nullptr, C, C, C, 1536, 0,    1},  // QK1
      {q0_b,  WT[2], bv1,  vT1,  nullptr, nullptr, nullptr, C, C, C, 0,    1024, 2},  // V1
      {qq,    WT[8], bKm,  Q3h,  K2i,     K3i,     nullptr, C, C, C, 768,  0,    1},  // Km (split)
      {imAB,  WT[6], bVm,  vT2i, vT3i,    nullptr, nullptr, C, C, C, 0,    1024, 2},  // Vm (split)
    };
    int Ms[4] = {B * N, B * N, 2 * B * N, 2 * B * N};
    int Ns[4] = {1536, C, 2304, 1536};
    packN(stream, as, Ms, Ns, 4);
  }
  {
    FArgs f1 = {QKh, attC, {QKh + 768, QKh + 768, QKh + 768}, {vT1, vT1, vT1},
                {0, 0, 0}, {7, 7, 7}, 1536, 1536, (long)N * 1536, (long)NC};
    k_flash<1><<<dim3(16, B * Hh), 256, 0, stream>>>(f1);
  }
  gemm(stream, attC, WT[3], bo1, a1, 0, 0, B * N, C, C, C, C, C);
  k_ln<<<dim3(B * N), 256, 0, stream>>>(queries, change, a1, ln1w, ln1b, q1, q1b, pe, fc, qf);

  // ================= stage 2: cross-attn change -> [A,B,change] =================
  off = arena;
  bf16_t* Q2h   = (bf16_t*)alloc(BNC * 2);
  bf16_t* K2c   = (bf16_t*)alloc(BNC * 2);
  bf16_t* vT2c  = (bf16_t*)alloc(BNC * 2);
  bf16_t* attC2 = (bf16_t*)alloc(BNC * 2);
  float*  a2    = dof;

  {
    GArgs as[2] = {
      {qf,  WT[4], bQ2K2, Q2h,  K2c,    nullptr, nullptr, C, C, C, 768,  0,    1},  // Q2|K2c
      {q1b, WT[6], bv2,   vT2c, nullptr, nullptr, nullptr, C, C, C, 0,    1024, 2},  // V2c
    };
    int Ms[2] = {B * N, B * N};
    int Ns[2] = {1536, C};
    packN(stream, as, Ms, Ns, 2);
  }
  {
    FArgs f2 = {Q2h, attC2, {K2i, K2i, K2c}, {vT2i, vT2i, vT2c},
                {0, 4, 0}, {3, 3, 3}, C, C, (long)NC, (long)NC};
    k_flash<3><<<dim3(16, B * Hh), 256, 0, stream>>>(f2);
  }
  gemm(stream, attC2, WT[7], bo2, a2, 0, 0, B * N, C, C, C, C, C);
  k_ln<<<dim3(B * N), 256, 0, stream>>>(q1, (const float*)nullptr, a2, ln2w, ln2b, q2, q2b,
                                        (const float*)nullptr, (const float*)nullptr, (bf16_t*)nullptr);

  // ================= MLP =================
  off = arena;
  bf16_t* h1 = (bf16_t*)alloc((size_t)B * N * MLPD * 2);
  float*  a3 = dof;
  gemm(stream, q2b, WTm1, mb1, h1, 1, 1, B * N, MLPD, C, C, C, MLPD);
  gemm(stream, h1, WTm2, mb2, a3, 0, 0, B * N, C, MLPD, MLPD, MLPD, C);

  // ================= stage 3 =================
  off = arena;
  bf16_t* cf    = (bf16_t*)alloc(BNC * 2);
  bf16_t* chgb  = (bf16_t*)alloc(BNC * 2);
  bf16_t* K3c   = (bf16_t*)alloc(BNC * 2);
  bf16_t* vT3c  = (bf16_t*)alloc(BNC * 2);
  bf16_t* attC3 = (bf16_t*)alloc(2 * BNC * 2);

  k_ln<<<dim3(B * N), 256, 0, stream>>>(q2, (const float*)nullptr, a3, ln3w, ln3b, chg, chgb,
                                        pe, fc, cf);
  {
    GArgs as[2] = {
      {cf,   WT[9],  bk3, K3c,  nullptr, nullptr, nullptr, C, C, C, 768,  0,    1},
      {chgb, WT[10], bv3, vT3c, nullptr, nullptr, nullptr, C, C, C, 0,    1024, 2},
    };
    int Ms[2] = {B * N, B * N};
    int Ns[2] = {C, C};
    packN(stream, as, Ms, Ns, 2);
  }
  {
    FArgs f3 = {Q3h, attC3, {K3i, K3c, K3c}, {vT3i, vT3c, vT3c},
                {0, 0, 0}, {7, 3, 3}, C, C, (long)NC, (long)NC};
    k_flash<2><<<dim3(16, 2 * B * Hh), 256, 0, stream>>>(f3);
  }
  {
    GArgs as[1] = {{attC3, WT[11], bo3, dof, nullptr, nullptr, qq, C, C, C, C, 0, 3}};
    int Ms[1] = {2 * B * N};
    int Ns[1] = {C};
    packN(stream, as, Ms, Ns, 1);
  }
}

// Round 26
// 622.340 us; speedup vs baseline: 1.6253x; 1.6253x over previous
//
#include <hip/hip_runtime.h>
#include <hip/hip_bf16.h>
#include <math.h>

typedef short bf16x8 __attribute__((ext_vector_type(8)));
typedef float f32x4 __attribute__((ext_vector_type(4)));
using bf16_t = __hip_bfloat16;

#define DEV static __device__ __forceinline__

DEV unsigned short f2bu(float x) {
  bf16_t h = __float2bfloat16(x);
  unsigned short u;
  __builtin_memcpy(&u, &h, 2);
  return u;
}
DEV void st4(bf16_t* p, float a, float b, float c, float d) {
  ushort4 u;
  u.x = f2bu(a); u.y = f2bu(b); u.z = f2bu(c); u.w = f2bu(d);
  *reinterpret_cast<ushort4*>(p) = u;
}

// bijective XCD swizzle (m204)
DEV int xcd_swz(int orig, int tot) {
  int q = tot >> 3, r = tot & 7;
  int xcd = orig & 7, pos = orig >> 3;
  int base = xcd < r ? xcd * (q + 1) : r * (q + 1) + (xcd - r) * q;
  return base + pos;
}

// async 16B/lane global -> LDS (wave-uniform LDS base + lane*16)
DEV void async_copy16(const bf16_t* g, bf16_t* lds) {
  __builtin_amdgcn_global_load_lds(
      (const __attribute__((address_space(1))) unsigned int*)g,
      (__attribute__((address_space(3))) unsigned int*)lds, 16, 0, 0);
}

// ---------------- batched weight transpose (13 square 768x768 weights, per-entry scale) --------
struct WPack {
  const float* s[13];
  bf16_t* d[13];
  float scale[13];
};

__global__ __launch_bounds__(256) void k_wt13(WPack pk) {
  __shared__ float tile[32][33];
  int z = blockIdx.z;
  const float* W = pk.s[z];
  bf16_t* WT = pk.d[z];
  float scale = pk.scale[z];
  int i0 = blockIdx.x * 32;
  int o0 = blockIdx.y * 32;
  int tx = threadIdx.x & 31, ty = threadIdx.x >> 5;
  for (int r = ty; r < 32; r += 8)
    tile[r][tx] = W[(size_t)(i0 + r) * 768 + (o0 + tx)];
  __syncthreads();
  for (int r = ty; r < 32; r += 8)
    WT[(size_t)(o0 + r) * 768 + (i0 + tx)] = __float2bfloat16(tile[tx][r] * scale);
}

// ---------------- single weight transpose + bf16 convert: W[in][out] -> WT[out][in] ----------------
__global__ __launch_bounds__(256) void k_wt(const float* __restrict__ W, bf16_t* __restrict__ WT,
                                            int in_dim, int out_dim) {
  __shared__ float tile[32][33];
  int i0 = blockIdx.x * 32;
  int o0 = blockIdx.y * 32;
  int tx = threadIdx.x & 31, ty = threadIdx.x >> 5;
  for (int r = ty; r < 32; r += 8)
    tile[r][tx] = W[(size_t)(i0 + r) * out_dim + (o0 + tx)];
  __syncthreads();
  for (int r = ty; r < 32; r += 8)
    WT[(size_t)(o0 + r) * in_dim + (i0 + tx)] = __float2bfloat16(tile[tx][r]);
}

// ---------------- bias concat: out = [s0*a0 ; s1 ; s2] (segments of 768) ----------------
__global__ __launch_bounds__(256) void k_bcat(const float* __restrict__ s0, const float* __restrict__ s1,
                                              const float* __restrict__ s2, float a0,
                                              float* __restrict__ out, int nseg) {
  int i = blockIdx.x * 256 + threadIdx.x;
  if (i >= nseg * 768) return;
  int seg = i / 768, c = i - seg * 768;
  const float* s = seg == 0 ? s0 : (seg == 1 ? s1 : s2);
  out[i] = s[c] * (seg == 0 ? a0 : 1.0f);
}

// ---------------- stage-1 elementwise prep ----------------
__global__ __launch_bounds__(256) void k_prep1(const float4* __restrict__ q, const float4* __restrict__ ce,
                                               const float4* __restrict__ pe,
                                               bf16_t* __restrict__ qpe_b, bf16_t* __restrict__ q0_b, int n4) {
  int i = blockIdx.x * 256 + threadIdx.x;
  if (i >= n4) return;
  float4 a = q[i], b = ce[i], p = pe[i];
  float sx = a.x + b.x, sy = a.y + b.y, sz = a.z + b.z, sw = a.w + b.w;
  st4(q0_b + 4 * (size_t)i, sx, sy, sz, sw);
  st4(qpe_b + 4 * (size_t)i, sx + p.x, sy + p.y, sz + p.z, sw + p.w);
}

// ---------------- build qq (=img+pe+flag) and imAB (=raw img) for rows = 2B*N ----------------
__global__ __launch_bounds__(256) void k_buildqq(const float* __restrict__ imA, const float* __restrict__ imB,
                                                 const float* __restrict__ pe, const float* __restrict__ fa,
                                                 const float* __restrict__ fb, bf16_t* __restrict__ qq,
                                                 bf16_t* __restrict__ imAB) {
  int idx = blockIdx.x * 256 + threadIdx.x;
  int c4 = idx % 192; int rem = idx / 192;
  int n = rem & 1023; int bb = rem >> 10;
  int b = bb & 3, isB = bb >> 2;
  int c = c4 * 4;
  size_t tok = (size_t)(b * 1024 + n) * 768 + c;
  float4 s = *(const float4*)((isB ? imB : imA) + tok);
  float4 p = *(const float4*)(pe + tok);
  float4 f = *(const float4*)((isB ? fb : fa) + c);
  size_t o = (size_t)rem * 768 + c;
  st4(imAB + o, s.x, s.y, s.z, s.w);
  st4(qq + o, s.x + p.x + f.x, s.y + p.y + f.y, s.z + p.z + f.z, s.w + p.w + f.w);
}

// ---------------- flash attention with segmented K/V; T14 async-STAGE (spill-proofed) --------------
// Tile t+1's K/V loads fly under tile t's compute in EIGHT NAMED uint4 registers (no arrays,
// no lambda -> cannot be demoted to scratch); segment pointers are compile-time-indexed under
// the unrolled segment loop. Arithmetic order identical to r23.
struct FArgs {
  const bf16_t* Q; bf16_t* O;
  const bf16_t* Kp[3]; const bf16_t* Vp[3];
  int badd[3], bmask[3];
  int ldq, ldk;
  long qStrideB, oStrideB;
};

template<int NSEG>
__global__ __launch_bounds__(256, 3) void k_flash(FArgs fa) {
  const int z = blockIdx.y; const int b = z / 6, h = z % 6;
  const bf16_t* Qb = fa.Q + (size_t)b * fa.qStrideB + h * 128;
  bf16_t* Ob = fa.O + (size_t)b * fa.oStrideB + h * 128;
  const int q0 = blockIdx.x * 64;
  const int tid = threadIdx.x, lane = tid & 63, w = tid >> 6;
  const int g = lane >> 4, c = lane & 15;

  __shared__ bf16_t Ks[64][136];
  __shared__ bf16_t Vs[128][72];
  __shared__ bf16_t Ps[64][72];

  bf16x8 qf[4];
#pragma unroll
  for (int kk = 0; kk < 4; kk++)
    qf[kk] = *reinterpret_cast<const bf16x8*>(
        &Qb[(size_t)(q0 + w * 16 + c) * fa.ldq + kk * 32 + g * 8]);

  f32x4 oa[8];
  float m[4], l[4];
#pragma unroll
  for (int d = 0; d < 8; d++) { f32x4 zz = {0.f, 0.f, 0.f, 0.f}; oa[d] = zz; }
#pragma unroll
  for (int r = 0; r < 4; r++) { m[r] = -1.0e30f; l[r] = 0.f; }

  const int kr_ = tid >> 4, kc_ = (tid & 15) * 8;   // K: 16 rows/pass
  const int vr_ = tid >> 3, vc_ = (tid & 7) * 8;    // V: 32 rows/pass
  const int ldk = fa.ldk;

  uint4 kg0, kg1, kg2, kg3, vg0, vg1, vg2, vg3;

#define F_ISSUE(Kb_, Vb_, k0_)                                                                    \
  do {                                                                                            \
    kg0 = *reinterpret_cast<const uint4*>(&(Kb_)[(size_t)((k0_) + kr_) * ldk + kc_]);             \
    kg1 = *reinterpret_cast<const uint4*>(&(Kb_)[(size_t)((k0_) + 16 + kr_) * ldk + kc_]);        \
    kg2 = *reinterpret_cast<const uint4*>(&(Kb_)[(size_t)((k0_) + 32 + kr_) * ldk + kc_]);        \
    kg3 = *reinterpret_cast<const uint4*>(&(Kb_)[(size_t)((k0_) + 48 + kr_) * ldk + kc_]);        \
    vg0 = *reinterpret_cast<const uint4*>(&(Vb_)[(size_t)(vr_) * 1024 + (k0_) + vc_]);            \
    vg1 = *reinterpret_cast<const uint4*>(&(Vb_)[(size_t)(32 + vr_) * 1024 + (k0_) + vc_]);       \
    vg2 = *reinterpret_cast<const uint4*>(&(Vb_)[(size_t)(64 + vr_) * 1024 + (k0_) + vc_]);       \
    vg3 = *reinterpret_cast<const uint4*>(&(Vb_)[(size_t)(96 + vr_) * 1024 + (k0_) + vc_]);       \
  } while (0)

  // prologue: issue segment 0, tile 0 (compile-time segment index)
  {
    const int bi0 = fa.badd[0] + (b & fa.bmask[0]);
    const bf16_t* Kb0 = fa.Kp[0] + (size_t)bi0 * 1024 * ldk + h * 128;
    const bf16_t* Vb0 = fa.Vp[0] + (size_t)(bi0 * 6 + h) * 128 * 1024;
    F_ISSUE(Kb0, Vb0, 0);
  }

#pragma unroll
  for (int s = 0; s < NSEG; ++s) {
    const int bi = fa.badd[s] + (b & fa.bmask[s]);
    const bf16_t* Kb = fa.Kp[s] + (size_t)bi * 1024 * ldk + h * 128;
    const bf16_t* Vb = fa.Vp[s] + (size_t)(bi * 6 + h) * 128 * 1024;
    for (int t = 0; t < 16; ++t) {
      // commit tile (s,t): safe — closing barrier of previous round drained all reads
      *reinterpret_cast<uint4*>(&Ks[kr_][kc_]) = kg0;
      *reinterpret_cast<uint4*>(&Ks[16 + kr_][kc_]) = kg1;
      *reinterpret_cast<uint4*>(&Ks[32 + kr_][kc_]) = kg2;
      *reinterpret_cast<uint4*>(&Ks[48 + kr_][kc_]) = kg3;
      *reinterpret_cast<uint4*>(&Vs[vr_][vc_]) = vg0;
      *reinterpret_cast<uint4*>(&Vs[32 + vr_][vc_]) = vg1;
      *reinterpret_cast<uint4*>(&Vs[64 + vr_][vc_]) = vg2;
      *reinterpret_cast<uint4*>(&Vs[96 + vr_][vc_]) = vg3;
      __syncthreads();

      // issue next tile; flies under this tile's compute
      if (t < 15) {
        F_ISSUE(Kb, Vb, (t + 1) << 6);
      } else if (s + 1 < NSEG) {           // statically resolved under the unroll
        const int bi2 = fa.badd[s + 1] + (b & fa.bmask[s + 1]);
        const bf16_t* Kb2 = fa.Kp[s + 1] + (size_t)bi2 * 1024 * ldk + h * 128;
        const bf16_t* Vb2 = fa.Vp[s + 1] + (size_t)(bi2 * 6 + h) * 128 * 1024;
        F_ISSUE(Kb2, Vb2, 0);
      }

      f32x4 sx[4];
#pragma unroll
      for (int j = 0; j < 4; j++) { f32x4 zz = {0.f, 0.f, 0.f, 0.f}; sx[j] = zz; }
      __builtin_amdgcn_s_setprio(1);
#pragma unroll
      for (int kk = 0; kk < 4; kk++)
#pragma unroll
        for (int j = 0; j < 4; j++) {
          bf16x8 kf = *reinterpret_cast<const bf16x8*>(&Ks[j * 16 + c][kk * 32 + g * 8]);
          sx[j] = __builtin_amdgcn_mfma_f32_16x16x32_bf16(qf[kk], kf, sx[j], 0, 0, 0);
        }
      __builtin_amdgcn_s_setprio(0);

      float tl[4];
#pragma unroll
      for (int r = 0; r < 4; r++)
        tl[r] = fmaxf(fmaxf(sx[0][r], sx[1][r]), fmaxf(sx[2][r], sx[3][r]));
      float ex = fmaxf(fmaxf(tl[0] - m[0], tl[1] - m[1]), fmaxf(tl[2] - m[2], tl[3] - m[3]));
      if (__any(ex > 8.0f)) {
#pragma unroll
        for (int r = 0; r < 4; r++) {
          float tv = tl[r];
          tv = fmaxf(tv, __shfl_xor(tv, 1));
          tv = fmaxf(tv, __shfl_xor(tv, 2));
          tv = fmaxf(tv, __shfl_xor(tv, 4));
          tv = fmaxf(tv, __shfl_xor(tv, 8));
          float mn = fmaxf(m[r], tv);
          float f = exp2f(m[r] - mn);
          m[r] = mn;
          l[r] *= f;
#pragma unroll
          for (int d = 0; d < 8; d++) oa[d][r] *= f;
        }
      }
#pragma unroll
      for (int j = 0; j < 4; j++)
#pragma unroll
        for (int r = 0; r < 4; r++) {
          float p = exp2f(sx[j][r] - m[r]);
          l[r] += p;
          Ps[w * 16 + g * 4 + r][j * 16 + c] = __float2bfloat16(p);
        }

      __builtin_amdgcn_s_setprio(1);
#pragma unroll
      for (int kk = 0; kk < 2; kk++) {
        bf16x8 pf = *reinterpret_cast<const bf16x8*>(&Ps[w * 16 + c][kk * 32 + g * 8]);
#pragma unroll
        for (int d = 0; d < 8; d++) {
          bf16x8 vf = *reinterpret_cast<const bf16x8*>(&Vs[d * 16 + c][kk * 32 + g * 8]);
          oa[d] = __builtin_amdgcn_mfma_f32_16x16x32_bf16(pf, vf, oa[d], 0, 0, 0);
        }
      }
      __builtin_amdgcn_s_setprio(0);
      __syncthreads();
    }
  }
#undef F_ISSUE

  float inv[4];
#pragma unroll
  for (int r = 0; r < 4; r++) {
    float t2 = l[r];
    t2 += __shfl_xor(t2, 1);
    t2 += __shfl_xor(t2, 2);
    t2 += __shfl_xor(t2, 4);
    t2 += __shfl_xor(t2, 8);
    inv[r] = 1.0f / t2;
  }
#pragma unroll
  for (int d = 0; d < 8; d++) {
    int col = d * 16 + c;
#pragma unroll
    for (int r = 0; r < 4; r++) {
      int row = q0 + w * 16 + g * 4 + r;
      Ob[(size_t)row * 768 + col] = __float2bfloat16(oa[d][r] * inv[r]);
    }
  }
}

// ---------------- fused residual + LayerNorm (+ optional pe/flag bf16 output) ----------------
__global__ __launch_bounds__(256) void k_ln(const float* __restrict__ X1, const float* __restrict__ X2,
                                            const float* __restrict__ A,
                                            const float* __restrict__ w, const float* __restrict__ bvec,
                                            float* __restrict__ outf, bf16_t* __restrict__ outb,
                                            const float* __restrict__ pe, const float* __restrict__ flag,
                                            bf16_t* __restrict__ outpf) {
  int row = blockIdx.x, tid = threadIdx.x;
  size_t base = (size_t)row * 768;
  float v0 = X1[base + tid] + A[base + tid];
  float v1 = X1[base + tid + 256] + A[base + tid + 256];
  float v2 = X1[base + tid + 512] + A[base + tid + 512];
  if (X2) {
    v0 += X2[base + tid]; v1 += X2[base + tid + 256]; v2 += X2[base + tid + 512];
  }
  float s = v0 + v1 + v2;
  for (int o = 32; o; o >>= 1) s += __shfl_xor(s, o);
  __shared__ float sm[8];
  int wv = tid >> 6, ln = tid & 63;
  if (ln == 0) sm[wv] = s;
  __syncthreads();
  s = sm[0] + sm[1] + sm[2] + sm[3];
  float mean = s * (1.0f / 768.0f);
  float d0 = v0 - mean, d1 = v1 - mean, d2 = v2 - mean;
  float ss = d0 * d0 + d1 * d1 + d2 * d2;
  for (int o = 32; o; o >>= 1) ss += __shfl_xor(ss, o);
  if (ln == 0) sm[4 + wv] = ss;
  __syncthreads();
  ss = sm[4] + sm[5] + sm[6] + sm[7];
  float rstd = rsqrtf(ss * (1.0f / 768.0f) + 1e-5f);
  float o0 = d0 * rstd * w[tid] + bvec[tid];
  float o1 = d1 * rstd * w[tid + 256] + bvec[tid + 256];
  float o2 = d2 * rstd * w[tid + 512] + bvec[tid + 512];
  outf[base + tid] = o0; outf[base + tid + 256] = o1; outf[base + tid + 512] = o2;
  if (outb) {
    outb[base + tid] = __float2bfloat16(o0);
    outb[base + tid + 256] = __float2bfloat16(o1);
    outb[base + tid + 512] = __float2bfloat16(o2);
  }
  if (outpf) {
    outpf[base + tid] = __float2bfloat16(o0 + pe[base + tid] + flag[tid]);
    outpf[base + tid + 256] = __float2bfloat16(o1 + pe[base + tid + 256] + flag[tid + 256]);
    outpf[base + tid + 512] = __float2bfloat16(o2 + pe[base + tid + 512] + flag[tid + 512]);
  }
}

// ---------------- packed multi-GEMM (up to 7), with per-768-col output split ----------------
struct GArgs {
  const bf16_t* X; const bf16_t* Wt; const float* bias;
  void* O0; void* O1; void* O2;
  const bf16_t* resid;
  int K, ldx, ldw, ldo, vNk, mode;
};
struct GPack {
  GArgs a[7];
  int cum[7];
  int nx[7];
  int tot;
};

__global__ __launch_bounds__(256, 2) void k_gemmN(GPack pk) {
  GArgs a; int gbase, nx;
  int sidx = xcd_swz(blockIdx.x, pk.tot);
  {
    int idx = sidx;
    if (idx < pk.cum[0])      { a = pk.a[0]; gbase = 0;          nx = pk.nx[0]; }
    else if (idx < pk.cum[1]) { a = pk.a[1]; gbase = pk.cum[0];  nx = pk.nx[1]; }
    else if (idx < pk.cum[2]) { a = pk.a[2]; gbase = pk.cum[1];  nx = pk.nx[2]; }
    else if (idx < pk.cum[3]) { a = pk.a[3]; gbase = pk.cum[2];  nx = pk.nx[3]; }
    else if (idx < pk.cum[4]) { a = pk.a[4]; gbase = pk.cum[3];  nx = pk.nx[4]; }
    else if (idx < pk.cum[5]) { a = pk.a[5]; gbase = pk.cum[4];  nx = pk.nx[5]; }
    else                      { a = pk.a[6]; gbase = pk.cum[5];  nx = pk.nx[6]; }
  }
  int idx = sidx - gbase;
  const int brow = (idx / nx) * 128;
  const int bcol = (idx % nx) * 128;

  __shared__ bf16_t As[128 * 32];
  __shared__ bf16_t Bs[128 * 32];

  const int tid = threadIdx.x;
  const int lane = tid & 63;
  const int wave = tid >> 6;
  const int wr = wave >> 1;
  const int wc = wave & 1;

  f32x4 acc[4][4];
#pragma unroll
  for (int i = 0; i < 4; i++)
#pragma unroll
    for (int j = 0; j < 4; j++) {
      f32x4 zz = {0.f, 0.f, 0.f, 0.f};
      acc[i][j] = zz;
    }

  const int sr = lane >> 2;
  const int sc = (lane & 3) * 8;
  const int lrow = lane & 15;
  const int kch = (lane >> 4) * 8;

  const int nK = a.K >> 5;
  for (int kk = 0; kk < nK; ++kk) {
    const int k0 = kk << 5;
#pragma unroll
    for (int q = 0; q < 2; q++) {
      const int rows = wave * 32 + q * 16;
      async_copy16(a.X + (size_t)(brow + rows + sr) * a.ldx + k0 + sc, As + rows * 32);
      async_copy16(a.Wt + (size_t)(bcol + rows + sr) * a.ldw + k0 + sc, Bs + rows * 32);
    }
    __syncthreads();

    bf16x8 afr[4], bfr[4];
#pragma unroll
    for (int i = 0; i < 4; i++)
      afr[i] = *reinterpret_cast<const bf16x8*>(&As[(wr * 64 + i * 16 + lrow) * 32 + kch]);
#pragma unroll
    for (int j = 0; j < 4; j++)
      bfr[j] = *reinterpret_cast<const bf16x8*>(&Bs[(wc * 64 + j * 16 + lrow) * 32 + kch]);
#pragma unroll
    for (int i = 0; i < 4; i++)
#pragma unroll
      for (int j = 0; j < 4; j++)
        acc[i][j] = __builtin_amdgcn_mfma_f32_16x16x32_bf16(afr[i], bfr[j], acc[i][j], 0, 0, 0);
    __syncthreads();
  }

  const int lcol = lane & 15;
  const int lrow4 = (lane >> 4) * 4;

  int seg = 0;
  if (a.O1) seg = bcol / 768;
  void* ob = seg == 0 ? a.O0 : (seg == 1 ? a.O1 : a.O2);
  const int cofs = seg * 768;

  if (a.mode == 2) {
    const int bi = brow / a.vNk;
    const int n0 = brow - bi * a.vNk;
#pragma unroll
    for (int i = 0; i < 4; i++) {
      int rloc = n0 + wr * 64 + i * 16 + lrow4;
#pragma unroll
      for (int j = 0; j < 4; j++) {
        int colf = bcol + wc * 64 + j * 16 + lcol;
        int col = colf - cofs;
        int hh = col >> 7, dd = col & 127;
        float bv = a.bias[colf];
        ushort4 u;
        u.x = f2bu(acc[i][j][0] + bv);
        u.y = f2bu(acc[i][j][1] + bv);
        u.z = f2bu(acc[i][j][2] + bv);
        u.w = f2bu(acc[i][j][3] + bv);
        bf16_t* dst = reinterpret_cast<bf16_t*>(ob) +
                      ((size_t)(bi * 6 + hh) * 128 + dd) * (size_t)a.vNk + rloc;
        *reinterpret_cast<ushort4*>(dst) = u;
      }
    }
  } else if (a.mode == 3) {
#pragma unroll
    for (int i = 0; i < 4; i++) {
      int row0 = brow + wr * 64 + i * 16 + lrow4;
#pragma unroll
      for (int j = 0; j < 4; j++) {
        int col = bcol + wc * 64 + j * 16 + lcol;
        float bv = a.bias[col];
#pragma unroll
        for (int r = 0; r < 4; r++) {
          size_t idx2 = (size_t)(row0 + r) * a.ldo + col;
          float rv = __bfloat162float(a.resid[(size_t)(row0 + r) * 768 + col]);
          reinterpret_cast<float*>(a.O0)[idx2] = acc[i][j][r] + bv + rv;
        }
      }
    }
  } else {
#pragma unroll
    for (int i = 0; i < 4; i++) {
      int row0 = brow + wr * 64 + i * 16 + lrow4;
#pragma unroll
      for (int j = 0; j < 4; j++) {
        int colf = bcol + wc * 64 + j * 16 + lcol;
        int col = colf - cofs;
        float bv = a.bias[colf];
#pragma unroll
        for (int r = 0; r < 4; r++)
          reinterpret_cast<bf16_t*>(ob)[(size_t)(row0 + r) * a.ldo + col] =
              __float2bfloat16(acc[i][j][r] + bv);
      }
    }
  }
}

static inline void packN(hipStream_t st, const GArgs* as, const int* Ms, const int* Ns, int n) {
  GPack pk;
  int tot = 0;
  for (int i = 0; i < 7; ++i) {
    int j = i < n ? i : n - 1;
    pk.a[i] = as[j];
    pk.nx[i] = Ns[j] / 128;
    if (i < n) tot += (Ns[j] / 128) * (Ms[j] / 128);
    pk.cum[i] = tot;
  }
  pk.tot = tot;
  k_gemmN<<<dim3(tot), 256, 0, st>>>(pk);
}

// ---------------- single bf16 MFMA GEMM (f32/bf16 out, optional GELU), T1-swizzled ----------------
template<int OUTBF, int GELU>
__global__ __launch_bounds__(256, 2) void k_gemm(
    const bf16_t* __restrict__ X, const bf16_t* __restrict__ Wt,
    const float* __restrict__ bias, void* __restrict__ Out,
    int M, int Nout, int K, int ldx, int ldw, int ldo, float alpha) {
  int tot = gridDim.x * gridDim.y;
  int lin = blockIdx.y * gridDim.x + blockIdx.x;
  int sidx = xcd_swz(lin, tot);
  const int brow = (sidx / gridDim.x) * 128;
  const int bcol = (sidx % gridDim.x) * 128;

  __shared__ bf16_t As[128 * 32];
  __shared__ bf16_t Bs[128 * 32];

  const int tid = threadIdx.x;
  const int lane = tid & 63;
  const int wave = tid >> 6;
  const int wr = wave >> 1;
  const int wc = wave & 1;

  f32x4 acc[4][4];
#pragma unroll
  for (int i = 0; i < 4; i++)
#pragma unroll
    for (int j = 0; j < 4; j++) {
      f32x4 zz = {0.f, 0.f, 0.f, 0.f};
      acc[i][j] = zz;
    }

  const int sr = lane >> 2;
  const int sc = (lane & 3) * 8;
  const int lrow = lane & 15;
  const int kch = (lane >> 4) * 8;

  const int nK = K >> 5;
  for (int kk = 0; kk < nK; ++kk) {
    const int k0 = kk << 5;
#pragma unroll
    for (int q = 0; q < 2; q++) {
      const int rows = wave * 32 + q * 16;
      async_copy16(X + (size_t)(brow + rows + sr) * ldx + k0 + sc, As + rows * 32);
      async_copy16(Wt + (size_t)(bcol + rows + sr) * ldw + k0 + sc, Bs + rows * 32);
    }
    __syncthreads();

    bf16x8 afr[4], bfr[4];
#pragma unroll
    for (int i = 0; i < 4; i++)
      afr[i] = *reinterpret_cast<const bf16x8*>(&As[(wr * 64 + i * 16 + lrow) * 32 + kch]);
#pragma unroll
    for (int j = 0; j < 4; j++)
      bfr[j] = *reinterpret_cast<const bf16x8*>(&Bs[(wc * 64 + j * 16 + lrow) * 32 + kch]);
#pragma unroll
    for (int i = 0; i < 4; i++)
#pragma unroll
      for (int j = 0; j < 4; j++)
        acc[i][j] = __builtin_amdgcn_mfma_f32_16x16x32_bf16(afr[i], bfr[j], acc[i][j], 0, 0, 0);
    __syncthreads();
  }

  const int lcol = lane & 15;
  const int lrow4 = (lane >> 4) * 4;

#pragma unroll
  for (int i = 0; i < 4; i++) {
    int row0 = brow + wr * 64 + i * 16 + lrow4;
#pragma unroll
    for (int j = 0; j < 4; j++) {
      int col = bcol + wc * 64 + j * 16 + lcol;
      float bv = bias ? bias[col] : 0.0f;
#pragma unroll
      for (int r = 0; r < 4; r++) {
        float v = (acc[i][j][r] + bv) * alpha;
        if (GELU) v = 0.5f * v * (1.0f + erff(v * 0.70710678118f));
        size_t idx = (size_t)(row0 + r) * ldo + col;
        if (OUTBF) reinterpret_cast<bf16_t*>(Out)[idx] = __float2bfloat16(v);
        else reinterpret_cast<float*>(Out)[idx] = v;
      }
    }
  }
}

static inline void gemm(hipStream_t st, const bf16_t* X, const bf16_t* Wt, const float* bias,
                        void* out, int outBf, int gelu, int M, int N, int K,
                        int ldx, int ldw, int ldo, float alpha = 1.0f) {
  dim3 g(N / 128, M / 128), blk(256);
  if (outBf) {
    if (gelu) k_gemm<1, 1><<<g, blk, 0, st>>>(X, Wt, bias, out, M, N, K, ldx, ldw, ldo, alpha);
    else      k_gemm<1, 0><<<g, blk, 0, st>>>(X, Wt, bias, out, M, N, K, ldx, ldw, ldo, alpha);
  } else      k_gemm<0, 0><<<g, blk, 0, st>>>(X, Wt, bias, out, M, N, K, ldx, ldw, ldo, alpha);
}

extern "C" void kernel_launch(void* const* d_in, const int* in_sizes, int n_in,
                              void* d_out, int out_size, void* d_ws, size_t ws_size,
                              hipStream_t stream) {
  (void)in_sizes; (void)n_in; (void)out_size; (void)ws_size;
  constexpr int B = 4, N = 1024, C = 768, Hh = 6, MLPD = 2304;
  constexpr size_t BNC = (size_t)B * N * C;
  constexpr size_t NC  = (size_t)N * C;
  const float qalpha = 0.08838834764831845f * 1.4426950408889634f;   // 1/sqrt(128) * log2(e)

  const float* queries = (const float*)d_in[0];
  const float* change  = (const float*)d_in[1];
  const float* imA     = (const float*)d_in[2];
  const float* imB     = (const float*)d_in[3];
  const float* pe      = (const float*)d_in[4];
  const float* bq1 = (const float*)d_in[6];  const float* bk1 = (const float*)d_in[8];
  const float* bv1 = (const float*)d_in[10]; const float* bo1 = (const float*)d_in[12];
  const float* bq2 = (const float*)d_in[14]; const float* bk2 = (const float*)d_in[16];
  const float* bv2 = (const float*)d_in[18]; const float* bo2 = (const float*)d_in[20];
  const float* bq3 = (const float*)d_in[22]; const float* bk3 = (const float*)d_in[24];
  const float* bv3 = (const float*)d_in[26]; const float* bo3 = (const float*)d_in[28];
  const float* ln1w = (const float*)d_in[29]; const float* ln1b = (const float*)d_in[30];
  const float* ln2w = (const float*)d_in[31]; const float* ln2b = (const float*)d_in[32];
  const float* ln3w = (const float*)d_in[33]; const float* ln3b = (const float*)d_in[34];
  const float* mb1 = (const float*)d_in[36]; const float* mb2 = (const float*)d_in[38];
  const float* fa = (const float*)d_in[39];
  const float* fb = (const float*)d_in[40];
  const float* fc = (const float*)d_in[41];

  char* base = (char*)d_ws;
  size_t off = 0;
  auto alloc = [&](size_t bytes) -> void* {
    void* p = base + off;
    off += (bytes + 255) & ~(size_t)255;
    return p;
  };

  // ---- persistent weights; ORDER MATTERS (merged views need adjacency) ----
  bf16_t* WT[12]; bf16_t* WT5b; bf16_t* WTm1; bf16_t* WTm2;
  WT[0] = (bf16_t*)alloc((size_t)768 * 768 * 2);
  WT[1] = (bf16_t*)alloc((size_t)768 * 768 * 2);
  WT[2] = (bf16_t*)alloc((size_t)768 * 768 * 2);
  WT[3] = (bf16_t*)alloc((size_t)768 * 768 * 2);
  WT[8] = (bf16_t*)alloc((size_t)768 * 768 * 2);   // Km view: [Wq3|Wk2|Wk3]
  WT[5] = (bf16_t*)alloc((size_t)768 * 768 * 2);
  WT[9] = (bf16_t*)alloc((size_t)768 * 768 * 2);
  WT[6] = (bf16_t*)alloc((size_t)768 * 768 * 2);   // Vm view: [Wv2|Wv3]
  WT[10] = (bf16_t*)alloc((size_t)768 * 768 * 2);
  WT[4] = (bf16_t*)alloc((size_t)768 * 768 * 2);   // Q2K2 view: [Wq2|Wk2']
  WT5b  = (bf16_t*)alloc((size_t)768 * 768 * 2);
  WT[7] = (bf16_t*)alloc((size_t)768 * 768 * 2);
  WT[11] = (bf16_t*)alloc((size_t)768 * 768 * 2);
  WTm1 = (bf16_t*)alloc((size_t)768 * 2304 * 2);
  WTm2 = (bf16_t*)alloc((size_t)2304 * 768 * 2);
  float* bqk1  = (float*)alloc(1536 * 4);
  float* bKm   = (float*)alloc(2304 * 4);
  float* bVm   = (float*)alloc(1536 * 4);
  float* bQ2K2 = (float*)alloc(1536 * 4);
  float*  q1  = (float*)alloc(BNC * 4);
  float*  q2  = (float*)alloc(BNC * 4);
  bf16_t* q2b = (bf16_t*)alloc(BNC * 2);
  bf16_t* q1b = (bf16_t*)alloc(BNC * 2);
  bf16_t* qf  = (bf16_t*)alloc(BNC * 2);
  bf16_t* qq   = (bf16_t*)alloc(2 * BNC * 2);   // img+pe+flag; lives to O3 residual
  bf16_t* Q3h  = (bf16_t*)alloc(2 * BNC * 2);
  bf16_t* K2i  = (bf16_t*)alloc(2 * BNC * 2);
  bf16_t* vT2i = (bf16_t*)alloc(2 * BNC * 2);
  bf16_t* K3i  = (bf16_t*)alloc(2 * BNC * 2);
  bf16_t* vT3i = (bf16_t*)alloc(2 * BNC * 2);
  const size_t arena = off;

  float* dof = (float*)d_out;                  // [0,2BNC) images, [2BNC,3BNC) change
  float* chg = dof + 2 * BNC;

  // weight transposes + bias concats
  {
    WPack pk;
    const int widx[12] = {5, 7, 9, 11, 13, 15, 17, 19, 21, 23, 25, 27};
    for (int i = 0; i < 12; i++) {
      pk.s[i] = (const float*)d_in[widx[i]];
      pk.d[i] = WT[i];
      pk.scale[i] = (i == 0 || i == 4 || i == 8) ? qalpha : 1.0f;
    }
    pk.s[12] = (const float*)d_in[15]; pk.d[12] = WT5b; pk.scale[12] = 1.0f;
    k_wt13<<<dim3(24, 24, 13), 256, 0, stream>>>(pk);
  }
  k_wt<<<dim3(24, 72), 256, 0, stream>>>((const float*)d_in[35], WTm1, 768, 2304);
  k_wt<<<dim3(72, 24), 256, 0, stream>>>((const float*)d_in[37], WTm2, 2304, 768);
  k_bcat<<<dim3(6), 256, 0, stream>>>(bq1, bk1, nullptr, qalpha, bqk1, 2);
  k_bcat<<<dim3(9), 256, 0, stream>>>(bq3, bk2, bk3, qalpha, bKm, 3);
  k_bcat<<<dim3(6), 256, 0, stream>>>(bv2, bv3, nullptr, 1.0f, bVm, 2);
  k_bcat<<<dim3(6), 256, 0, stream>>>(bq2, bk2, nullptr, qalpha, bQ2K2, 2);

  // ================= stage 1 + all input-only projections =================
  off = arena;
  bf16_t* qpe_b = (bf16_t*)alloc(BNC * 2);
  bf16_t* q0_b  = (bf16_t*)alloc(BNC * 2);
  bf16_t* imAB  = (bf16_t*)alloc(2 * BNC * 2);
  bf16_t* QKh   = (bf16_t*)alloc((size_t)B * N * 1536 * 2);
  bf16_t* vT1   = (bf16_t*)alloc(BNC * 2);
  bf16_t* attC  = (bf16_t*)alloc(BNC * 2);
  float*  a1    = dof;

  k_prep1<<<dim3((int)(BNC / 4 / 256)), 256, 0, stream>>>(
      (const float4*)queries, (const float4*)change, (const float4*)pe, qpe_b, q0_b, (int)(BNC / 4));
  k_buildqq<<<dim3((int)(2 * BNC / 4 / 256)), 256, 0, stream>>>(imA, imB, pe, fa, fb, qq, imAB);
  {
    GArgs as[4] = {
      {qpe_b, WT[0], bqk1, QKh,  nullptr, nullptr, nullptr, C, C, C, 1536, 0,    1},  // QK1
      {q0_b,  WT[2], bv1,  vT1,  nullptr, nullptr, nullptr, C, C, C, 0,    1024, 2},  // V1
      {qq,    WT[8], bKm,  Q3h,  K2i,     K3i,     nullptr, C, C, C, 768,  0,    1},  // Km (split)
      {imAB,  WT[6], bVm,  vT2i, vT3i,    nullptr, nullptr, C, C, C, 0,    1024, 2},  // Vm (split)
    };
    int Ms[4] = {B * N, B * N, 2 * B * N, 2 * B * N};
    int Ns[4] = {1536, C, 2304, 1536};
    packN(stream, as, Ms, Ns, 4);
  }
  {
    FArgs f1 = {QKh, attC, {QKh + 768, QKh + 768, QKh + 768}, {vT1, vT1, vT1},
                {0, 0, 0}, {7, 7, 7}, 1536, 1536, (long)N * 1536, (long)NC};
    k_flash<1><<<dim3(16, B * Hh), 256, 0, stream>>>(f1);
  }
  gemm(stream, attC, WT[3], bo1, a1, 0, 0, B * N, C, C, C, C, C);
  k_ln<<<dim3(B * N), 256, 0, stream>>>(queries, change, a1, ln1w, ln1b, q1, q1b, pe, fc, qf);

  // ================= stage 2: cross-attn change -> [A,B,change] =================
  off = arena;
  bf16_t* Q2h   = (bf16_t*)alloc(BNC * 2);
  bf16_t* K2c   = (bf16_t*)alloc(BNC * 2);
  bf16_t* vT2c  = (bf16_t*)alloc(BNC * 2);
  bf16_t* attC2 = (bf16_t*)alloc(BNC * 2);
  float*  a2    = dof;

  {
    GArgs as[2] = {
      {qf,  WT[4], bQ2K2, Q2h,  K2c,    nullptr, nullptr, C, C, C, 768,  0,    1},  // Q2|K2c
      {q1b, WT[6], bv2,   vT2c, nullptr, nullptr, nullptr, C, C, C, 0,    1024, 2},  // V2c
    };
    int Ms[2] = {B * N, B * N};
    int Ns[2] = {1536, C};
    packN(stream, as, Ms, Ns, 2);
  }
  {
    FArgs f2 = {Q2h, attC2, {K2i, K2i, K2c}, {vT2i, vT2i, vT2c},
                {0, 4, 0}, {3, 3, 3}, C, C, (long)NC, (long)NC};
    k_flash<3><<<dim3(16, B * Hh), 256, 0, stream>>>(f2);
  }
  gemm(stream, attC2, WT[7], bo2, a2, 0, 0, B * N, C, C, C, C, C);
  k_ln<<<dim3(B * N), 256, 0, stream>>>(q1, (const float*)nullptr, a2, ln2w, ln2b, q2, q2b,
                                        (const float*)nullptr, (const float*)nullptr, (bf16_t*)nullptr);

  // ================= MLP =================
  off = arena;
  bf16_t* h1 = (bf16_t*)alloc((size_t)B * N * MLPD * 2);
  float*  a3 = dof;
  gemm(stream, q2b, WTm1, mb1, h1, 1, 1, B * N, MLPD, C, C, C, MLPD);
  gemm(stream, h1, WTm2, mb2, a3, 0, 0, B * N, C, MLPD, MLPD, MLPD, C);

  // ================= stage 3 =================
  off = arena;
  bf16_t* cf    = (bf16_t*)alloc(BNC * 2);
  bf16_t* chgb  = (bf16_t*)alloc(BNC * 2);
  bf16_t* K3c   = (bf16_t*)alloc(BNC * 2);
  bf16_t* vT3c  = (bf16_t*)alloc(BNC * 2);
  bf16_t* attC3 = (bf16_t*)alloc(2 * BNC * 2);

  k_ln<<<dim3(B * N), 256, 0, stream>>>(q2, (const float*)nullptr, a3, ln3w, ln3b, chg, chgb,
                                        pe, fc, cf);
  {
    GArgs as[2] = {
      {cf,   WT[9],  bk3, K3c,  nullptr, nullptr, nullptr, C, C, C, 768,  0,    1},
      {chgb, WT[10], bv3, vT3c, nullptr, nullptr, nullptr, C, C, C, 0,    1024, 2},
    };
    int Ms[2] = {B * N, B * N};
    int Ns[2] = {C, C};
    packN(stream, as, Ms, Ns, 2);
  }
  {
    FArgs f3 = {Q3h, attC3, {K3i, K3c, K3c}, {vT3i, vT3c, vT3c},
                {0, 0, 0}, {7, 3, 3}, C, C, (long)NC, (long)NC};
    k_flash<2><<<dim3(16, 2 * B * Hh), 256, 0, stream>>>(f3);
  }
  {
    GArgs as[1] = {{attC3, WT[11], bo3, dof, nullptr, nullptr, qq, C, C, C, C, 0, 3}};
    int Ms[1] = {2 * B * N};
    int Ns[1] = {C};
    packN(stream, as, Ms, Ns, 1);
  }
}